// Round 16
// baseline (99.225 us; speedup 1.0000x reference)
//
#include <hip/hip_runtime.h>
#include <stdint.h>

#define B_ 4
#define L_ 2048
#define H_ 8
#define DK 64
#define M_ 256
#define DIM_ 512
#define NTOK (B_ * L_)
#define CHK 128
#define NC (L_ / CHK)
#define BH (B_ * H_)
#define RATIO 0.0625f
#define STABC 1e-5f

typedef unsigned short ushort_t;
typedef __attribute__((ext_vector_type(8))) short bf8v;   // 8 bf16 = 4 VGPR
typedef __attribute__((ext_vector_type(4))) float f4v;    // MFMA accumulator

#define MFMA16(a, b, c) __builtin_amdgcn_mfma_f32_16x16x32_bf16(a, b, c, 0, 0, 0)

__device__ __forceinline__ ushort_t f2bf(float f) {
  uint32_t u = __float_as_uint(f);
  return (ushort_t)((u + 0x7fffu + ((u >> 16) & 1u)) >> 16);
}
__device__ __forceinline__ float bf2f(ushort_t u) { return __uint_as_float(((uint32_t)u) << 16); }

__device__ __forceinline__ void gll16(const void* g, void* l) {
  __builtin_amdgcn_global_load_lds((const __attribute__((address_space(1))) void*)g,
                                   (__attribute__((address_space(3))) void*)l, 16, 0, 0);
}

// XOR-swizzled LDS tiles; row strides 128/256/512 B
__device__ __forceinline__ bf8v ldfrag(const ushort_t* base, int row, int cb) {
  return *(const bf8v*)((const char*)base + row * 128 + (cb ^ ((row & 7) << 4)));
}
__device__ __forceinline__ bf8v ldfrag256(const ushort_t* base, int row, int cb) {
  return *(const bf8v*)((const char*)base + row * 256 + (cb ^ ((row & 7) << 4)));
}
__device__ __forceinline__ bf8v ldfrag512(const ushort_t* base, int row, int cb) {
  return *(const bf8v*)((const char*)base + row * 512 + (cb ^ ((row & 7) << 4)));
}

// ---------------- one-shot bf16 convert of q,k,v + weights + proj (r2 proven) ----------------
__global__ __launch_bounds__(256) void cvt_all(const float* __restrict__ q, const float* __restrict__ k,
                                               const float* __restrict__ v, const float* __restrict__ wq,
                                               const float* __restrict__ wk, const float* __restrict__ wv,
                                               const float* __restrict__ wo, const float* __restrict__ pj,
                                               ushort_t* __restrict__ Xq, ushort_t* __restrict__ Xk,
                                               ushort_t* __restrict__ Xv, ushort_t* __restrict__ Wc) {
  int i = (blockIdx.x * 256 + threadIdx.x) * 8;
  const float* s;
  ushort_t* d;
  int soff, doff;
  if (i < 4194304)       { s = q;  d = Xq; soff = i;            doff = soff; }
  else if (i < 8388608)  { s = k;  d = Xk; soff = i - 4194304;  doff = soff; }
  else if (i < 12582912) { s = v;  d = Xv; soff = i - 8388608;  doff = soff; }
  else {
    int j = i - 12582912;
    d = Wc; doff = j;
    if (j < 262144)       { s = wq; soff = j; }
    else if (j < 524288)  { s = wk; soff = j - 262144; }
    else if (j < 786432)  { s = wv; soff = j - 524288; }
    else if (j < 1048576) { s = wo; soff = j - 786432; }
    else                  { s = pj; soff = j - 1048576; }
  }
  float4 a = *(const float4*)(s + soff);
  float4 b = *(const float4*)(s + soff + 4);
  union { ushort_t u[8]; uint4 vv; } o;
  o.u[0] = f2bf(a.x); o.u[1] = f2bf(a.y); o.u[2] = f2bf(a.z); o.u[3] = f2bf(a.w);
  o.u[4] = f2bf(b.x); o.u[5] = f2bf(b.y); o.u[6] = f2bf(b.z); o.u[7] = f2bf(b.w);
  *(uint4*)(d + doff) = o.vv;
}

// ---------------- Q/K/V projection GEMM: 128x256 tile, pure-gll16 dbuf (gemmo economics) ----------------
// grid (64, 2, 3): z=0 Xq->XHq, z=1 Xk->XHk, z=2 Xv->VT (transposed head-slices)
// LDS 96 KB: A bufs @0/@16384 (16 KB); B bufs @32768/@65536 (32 KB)
__global__ __launch_bounds__(512) void qkvgemm_k(const ushort_t* __restrict__ Xq, const ushort_t* __restrict__ Xk,
                                                 const ushort_t* __restrict__ Xv, const ushort_t* __restrict__ Wc,
                                                 const float* __restrict__ bq, const float* __restrict__ bk,
                                                 const float* __restrict__ bv, ushort_t* __restrict__ XHq,
                                                 ushort_t* __restrict__ XHk, ushort_t* __restrict__ VT) {
  __shared__ char SB[98304];
  ushort_t* Tt = (ushort_t*)SB;        // epilogue alias [128][136] = 34816 B (z==2)
  const int z = blockIdx.z;
  const ushort_t* A = (z == 0) ? Xq : (z == 1) ? Xk : Xv;
  const ushort_t* Bw = Wc + (size_t)z * 262144;
  const float* bias = (z == 0) ? bq : (z == 1) ? bk : bv;
  const int tid = threadIdx.x, lane = tid & 63, w = tid >> 6;   // w 0..7
  const int bm = blockIdx.x * 128, bn = blockIdx.y * 256;
  const int srow = w * 8 + (lane >> 3);
  const int scol = (((lane & 7) * 16) ^ ((lane >> 3) << 4)) >> 1;   // pre-swizzled source elem
  const int fr = lane & 15, ks = lane >> 4, fq = lane >> 4;
  const int wr = (w >> 2) * 64, wc = (w & 3) * 64;
  f4v acc[4][4] = {};
  // ---- prologue: stage t=0 into buffer 0 ----
#pragma unroll
  for (int i = 0; i < 2; ++i)
    gll16(A + (size_t)(bm + i * 64 + srow) * DIM_ + scol, SB + i * 8192 + w * 1024);
#pragma unroll
  for (int i = 0; i < 4; ++i)
    gll16(Bw + (size_t)(bn + i * 64 + srow) * DIM_ + scol, SB + 32768 + i * 8192 + w * 1024);
  __syncthreads();
  for (int t = 0; t < 8; ++t) {
    const ushort_t* curA = (const ushort_t*)(SB + (t & 1) * 16384);
    const ushort_t* curB = (const ushort_t*)(SB + 32768 + (t & 1) * 32768);
    char* nxtA = SB + ((t + 1) & 1) * 16384;
    char* nxtB = SB + 32768 + ((t + 1) & 1) * 32768;
    const int nk = (t + 1) * 64;
    if (t < 7) {   // issue-early: next tile via gll16, flies under the MFMA below
#pragma unroll
      for (int i = 0; i < 2; ++i)
        gll16(A + (size_t)(bm + i * 64 + srow) * DIM_ + nk + scol, nxtA + i * 8192 + w * 1024);
#pragma unroll
      for (int i = 0; i < 4; ++i)
        gll16(Bw + (size_t)(bn + i * 64 + srow) * DIM_ + nk + scol, nxtB + i * 8192 + w * 1024);
    }
#pragma unroll
    for (int kk = 0; kk < 2; ++kk) {
      const int cb = kk * 64 + ks * 16;
      bf8v av[4], bv2[4];
#pragma unroll
      for (int m = 0; m < 4; ++m) av[m] = ldfrag(curA, wr + m * 16 + fr, cb);
#pragma unroll
      for (int n = 0; n < 4; ++n) bv2[n] = ldfrag(curB, wc + n * 16 + fr, cb);
#pragma unroll
      for (int m = 0; m < 4; ++m)
#pragma unroll
        for (int n = 0; n < 4; ++n) acc[m][n] = MFMA16(av[m], bv2[n], acc[m][n]);
    }
    __syncthreads();
  }
  if (z == 2) {   // V path: transpose 256-col head slice -> VT[bh][64][2048], two 128-col halves
    for (int hh = 0; hh < 2; ++hh) {
      if (((w & 3) >> 1) == hh) {
        const int wcl = wc - hh * 128;   // 0 or 64
#pragma unroll
        for (int m = 0; m < 4; ++m)
#pragma unroll
          for (int n = 0; n < 4; ++n) {
            int cl = wcl + n * 16 + fr;
            float bsv = bias[bn + wc + n * 16 + fr];
#pragma unroll
            for (int j = 0; j < 4; ++j) {
              int rl = wr + m * 16 + fq * 4 + j;
              Tt[cl * 136 + rl] = f2bf(acc[m][n][j] + bsv);
            }
          }
      }
      __syncthreads();
      const int dl = tid >> 2, seg = tid & 3;
      const int c = bn + hh * 128 + dl;            // global dim col 0..511
      const int bh2 = (bm >> 11) * 8 + (c >> 6);
      const int drow = c & 63;
      size_t vbase = ((size_t)(bh2 * 64 + drow)) * L_ + (bm & 2047) + seg * 32;
#pragma unroll
      for (int qq = 0; qq < 4; ++qq)
        *(uint4*)&VT[vbase + qq * 8] = *(const uint4*)&Tt[dl * 136 + seg * 32 + qq * 8];
      __syncthreads();
    }
  } else {
    ushort_t* Y = (z == 0) ? XHq : XHk;
#pragma unroll
    for (int m = 0; m < 4; ++m)
#pragma unroll
      for (int n = 0; n < 4; ++n) {
        int col = bn + wc + n * 16 + fr;
        float bsv = bias[col];
#pragma unroll
        for (int j = 0; j < 4; ++j) {
          int row = bm + wr + m * 16 + fq * 4 + j;
          Y[(size_t)row * DIM_ + col] = f2bf(acc[m][n][j] + bsv);
        }
      }
  }
}

// ---------------- cp2: fused kp-feature + per-chunk partials (no kp store) ----------------
__global__ __launch_bounds__(256) void cp2_k(const ushort_t* __restrict__ XHk, const ushort_t* __restrict__ P,
                                             const ushort_t* __restrict__ VT, ushort_t* __restrict__ S) {
  __shared__ ushort_t Ps[256 * 64];    // proj (32 KB)
  __shared__ ushort_t Xs[128 * 64];    // XHk chunk, then [VT;ones] (16 KB)
  __shared__ ushort_t Kt[256 * 128];   // kpT [m][l], 256B rows swizzled (64 KB)
  const int ci = blockIdx.x, bh = blockIdx.y;
  const int b = bh >> 3, h = bh & 7;
  const int tid = threadIdx.x, lane = tid & 63, w = tid >> 6;
  const int srow = w * 8 + (lane >> 3);
  const int scol = (((lane & 7) * 16) ^ ((lane >> 3) << 4)) >> 1;
  const int fr = lane & 15, ks = lane >> 4, fq = lane >> 4;
  const int l0 = ci * CHK;
#pragma unroll
  for (int i = 0; i < 8; ++i)
    gll16(P + (size_t)(i * 32 + srow) * 64 + scol, (char*)Ps + i * 4096 + w * 1024);
#pragma unroll
  for (int i = 0; i < 4; ++i)
    gll16(XHk + (size_t)(b * L_ + l0 + i * 32 + srow) * DIM_ + h * 64 + scol, (char*)Xs + i * 4096 + w * 1024);
  __syncthreads();
  {
    f4v acc[4][8] = {};
#pragma unroll
    for (int kk = 0; kk < 2; ++kk) {
      const int cb = kk * 64 + ks * 16;
      bf8v av[4], bv[8];
#pragma unroll
      for (int m = 0; m < 4; ++m) av[m] = ldfrag(Ps, w * 64 + m * 16 + fr, cb);
#pragma unroll
      for (int n = 0; n < 8; ++n) bv[n] = ldfrag(Xs, n * 16 + fr, cb);
#pragma unroll
      for (int m = 0; m < 4; ++m)
#pragma unroll
        for (int n = 0; n < 8; ++n) acc[m][n] = MFMA16(av[m], bv[n], acc[m][n]);
    }
#pragma unroll
    for (int m = 0; m < 4; ++m)
#pragma unroll
      for (int n = 0; n < 8; ++n) {
        const int mb = w * 64 + m * 16 + fq * 4;
        const int ll = n * 16 + fr;
#pragma unroll
        for (int j = 0; j < 4; ++j) {
          float v = fmaxf(RATIO * acc[m][n][j], 0.f) + STABC;
          *(ushort_t*)((char*)Kt + (mb + j) * 256 + ((ll * 2) ^ (((mb + j) & 7) << 4))) = f2bf(v);
        }
      }
  }
  __syncthreads();
  f4v accS[5][4] = {};
  for (int kt = 0; kt < 2; ++kt) {
#pragma unroll
    for (int i = 0; i < 2; ++i)
      gll16(VT + ((size_t)bh * 64 + i * 32 + srow) * L_ + l0 + kt * 64 + scol, (char*)Xs + i * 4096 + w * 1024);
    if (tid < 32) ((uint32_t*)Xs)[2048 + tid] = 0x3f803f80u;
    __syncthreads();
#pragma unroll
    for (int kk = 0; kk < 2; ++kk) {
      const int cbA = kk * 64 + ks * 16;
      const int cbK = kt * 128 + kk * 64 + ks * 16;
      bf8v av[5], bv[4];
#pragma unroll
      for (int a = 0; a < 5; ++a) av[a] = ldfrag(Xs, a * 16 + fr, cbA);
#pragma unroll
      for (int n = 0; n < 4; ++n) bv[n] = ldfrag256(Kt, w * 64 + n * 16 + fr, cbK);
#pragma unroll
      for (int a = 0; a < 5; ++a)
#pragma unroll
        for (int n = 0; n < 4; ++n) accS[a][n] = MFMA16(av[a], bv[n], accS[a][n]);
    }
    __syncthreads();
  }
  const size_t base = ((size_t)bh * NC + ci) * 65;
#pragma unroll
  for (int a = 0; a < 5; ++a)
#pragma unroll
    for (int n = 0; n < 4; ++n)
#pragma unroll
      for (int j = 0; j < 4; ++j) {
        int row = a * 16 + fq * 4 + j;
        if (row < 65) S[(base + row) * M_ + w * 64 + n * 16 + fr] = f2bf(accS[a][n][j]);
      }
}

// ---------------- exclusive prefix over chunks ----------------
__global__ __launch_bounds__(256) void prefix2_k(ushort_t* __restrict__ S) {
  const int g = blockIdx.x * 256 + threadIdx.x;
  const int bh = g / 2080, r = g - bh * 2080;
  ushort_t* base = S + (size_t)bh * (NC * 65 * M_) + (size_t)r * 8;
  uint4 v[16];
#pragma unroll
  for (int ci = 0; ci < NC; ++ci) v[ci] = *(const uint4*)(base + (size_t)ci * (65 * M_));
  float c[8] = {};
#pragma unroll
  for (int ci = 0; ci < NC; ++ci) {
    union { uint4 u; ushort_t s[8]; } in, out;
    in.u = v[ci];
#pragma unroll
    for (int e = 0; e < 8; ++e) {
      float t = bf2f(in.s[e]);
      out.s[e] = f2bf(c[e]);
      c[e] += t;
    }
    *(uint4*)(base + (size_t)ci * (65 * M_)) = out.u;
  }
}

// ---------------- qkout4: in-LDS qp AND kp features + QK^T + qp@S + A@[VT;1] ----------------
__global__ __launch_bounds__(512) void qkout4_k(const ushort_t* __restrict__ XHq, const ushort_t* __restrict__ XHk,
                                                const ushort_t* __restrict__ P, const ushort_t* __restrict__ VT,
                                                const ushort_t* __restrict__ S, ushort_t* __restrict__ attn) {
  __shared__ char LB[147456];
  ushort_t* Qp  = (ushort_t*)LB;
  ushort_t* Pj  = (ushort_t*)(LB + 65536);   // At aliases this in phases 2/3
  ushort_t* Kps = (ushort_t*)(LB + 98304);
  ushort_t* R2  = (ushort_t*)(LB + 114688);
  ushort_t* Xk  = (ushort_t*)(LB + 131072);
  const int ci = blockIdx.x, bh = blockIdx.y;
  const int b = bh >> 3, h = bh & 7;
  const int tid = threadIdx.x, lane = tid & 63, w = tid >> 6;   // w 0..7
  const int srow = w * 8 + (lane >> 3);
  const int scol = (((lane & 7) * 16) ^ ((lane >> 3) << 4)) >> 1;
  const int fr = lane & 15, ks = lane >> 4, fq = lane >> 4;
  const int l0 = ci * CHK;
  const size_t tokb = (size_t)b * L_ + l0;
  const size_t sbase = ((size_t)bh * NC + ci) * 65;
  // ---- phase 0: stage proj + XHq + XHk; compute Qp ----
#pragma unroll
  for (int i = 0; i < 4; ++i)
    gll16(P + (size_t)(i * 64 + srow) * 64 + scol, (char*)Pj + i * 8192 + w * 1024);
#pragma unroll
  for (int i = 0; i < 2; ++i) {
    gll16(XHq + (tokb + i * 64 + srow) * DIM_ + h * 64 + scol, (char*)R2 + i * 8192 + w * 1024);
    gll16(XHk + (tokb + i * 64 + srow) * DIM_ + h * 64 + scol, (char*)Xk + i * 8192 + w * 1024);
  }
  __syncthreads();
  {
    f4v accF[2][8] = {};
#pragma unroll
    for (int kk = 0; kk < 2; ++kk) {
      const int cb = kk * 64 + ks * 16;
      bf8v av[2], bv[8];
#pragma unroll
      for (int m = 0; m < 2; ++m) av[m] = ldfrag(Pj, w * 32 + m * 16 + fr, cb);
#pragma unroll
      for (int n = 0; n < 8; ++n) bv[n] = ldfrag(R2, n * 16 + fr, cb);
#pragma unroll
      for (int m = 0; m < 2; ++m)
#pragma unroll
        for (int n = 0; n < 8; ++n) accF[m][n] = MFMA16(av[m], bv[n], accF[m][n]);
    }
#pragma unroll
    for (int m = 0; m < 2; ++m)
#pragma unroll
      for (int n = 0; n < 8; ++n) {
        const int mb = w * 32 + m * 16 + fq * 4;
        const int ll = n * 16 + fr;
        ushort_t bvv[4];
#pragma unroll
        for (int j = 0; j < 4; ++j)
          bvv[j] = f2bf(fmaxf(RATIO * accF[m][n][j], 0.f) + STABC);
        uint2 pk;
        pk.x = (uint32_t)bvv[0] | ((uint32_t)bvv[1] << 16);
        pk.y = (uint32_t)bvv[2] | ((uint32_t)bvv[3] << 16);
        *(uint2*)((char*)Qp + ll * 512 + ((mb * 2) ^ ((ll & 7) << 4))) = pk;
      }
  }
  __syncthreads();
  // ---- phase 1: per kt: Kp slice (in-LDS feat) + QK^T + qp@[S;sk] ----
  const int qr = (w & 3) * 32, qc = (w >> 2) * 64;
  const int orow = w * 16;
  f4v accA[2][4] = {};
  f4v acc2[5] = {};
  for (int kt = 0; kt < 4; ++kt) {
    gll16(S + (sbase + srow) * M_ + kt * 64 + scol, (char*)R2 + w * 1024);
    if (tid < 32)
      ((uint32_t*)R2)[2048 + tid] = ((const uint32_t*)(S + (sbase + 64) * M_ + kt * 64))[tid];
    {
      const int fi = w >> 1, tf0 = (w & 1) * 4;
      f4v accK[4] = {};
#pragma unroll
      for (int kk = 0; kk < 2; ++kk) {
        const int cb = kk * 64 + ks * 16;
        bf8v ap = ldfrag(Pj, kt * 64 + fi * 16 + fr, cb);
        bf8v bx[4];
#pragma unroll
        for (int t2 = 0; t2 < 4; ++t2) bx[t2] = ldfrag(Xk, (tf0 + t2) * 16 + fr, cb);
#pragma unroll
        for (int t2 = 0; t2 < 4; ++t2) accK[t2] = MFMA16(ap, bx[t2], accK[t2]);
      }
#pragma unroll
      for (int t2 = 0; t2 < 4; ++t2) {
        const int tt = (tf0 + t2) * 16 + fr;
        const int fl = fi * 16 + fq * 4;
#pragma unroll
        for (int j = 0; j < 4; ++j) {
          float v = fmaxf(RATIO * accK[t2][j], 0.f) + STABC;
          *(ushort_t*)((char*)Kps + tt * 128 + (((fl + j) * 2) ^ ((tt & 7) << 4))) = f2bf(v);
        }
      }
    }
    __syncthreads();
#pragma unroll
    for (int kk = 0; kk < 2; ++kk) {
      const int cb = kk * 64 + ks * 16;
      const int cbQ = kt * 128 + cb;
      bf8v aq[2], bk_[4], a2, sv[5];
#pragma unroll
      for (int m = 0; m < 2; ++m) aq[m] = ldfrag512(Qp, qr + m * 16 + fr, cbQ);
#pragma unroll
      for (int n = 0; n < 4; ++n) bk_[n] = ldfrag(Kps, qc + n * 16 + fr, cb);
#pragma unroll
      for (int m = 0; m < 2; ++m)
#pragma unroll
        for (int n = 0; n < 4; ++n) accA[m][n] = MFMA16(aq[m], bk_[n], accA[m][n]);
      a2 = ldfrag512(Qp, orow + fr, cbQ);
#pragma unroll
      for (int n = 0; n < 5; ++n) sv[n] = ldfrag(R2, n * 16 + fr, cb);
#pragma unroll
      for (int n = 0; n < 5; ++n) acc2[n] = MFMA16(a2, sv[n], acc2[n]);
    }
    __syncthreads();
  }
  // ---- phase 2: masked A -> At (aliases Pj) ----
#pragma unroll
  for (int m = 0; m < 2; ++m)
#pragma unroll
    for (int n = 0; n < 4; ++n)
#pragma unroll
      for (int j = 0; j < 4; ++j) {
        int row = qr + m * 16 + fq * 4 + j;
        int col = qc + n * 16 + fr;
        float v = (col <= row) ? accA[m][n][j] : 0.f;
        *(ushort_t*)((char*)Pj + row * 256 + ((col * 2) ^ ((row & 7) << 4))) = f2bf(v);
      }
  __syncthreads();
  // ---- phase 3: A @ [VT; ones] ----
  for (int kt2 = 0; kt2 < 2; ++kt2) {
    gll16(VT + ((size_t)bh * 64 + srow) * L_ + l0 + kt2 * 64 + scol, (char*)R2 + w * 1024);
    if (tid < 32) ((uint32_t*)R2)[2048 + tid] = 0x3f803f80u;
    __syncthreads();
#pragma unroll
    for (int kk = 0; kk < 2; ++kk) {
      const int cb = kk * 64 + ks * 16;
      bf8v a3, sv[5];
      a3 = ldfrag256(Pj, orow + fr, kt2 * 128 + cb);
#pragma unroll
      for (int n = 0; n < 5; ++n) sv[n] = ldfrag(R2, n * 16 + fr, cb);
#pragma unroll
      for (int n = 0; n < 5; ++n) acc2[n] = MFMA16(a3, sv[n], acc2[n]);
    }
    __syncthreads();
  }
  // ---- epilogue ----
  float dinv[4];
#pragma unroll
  for (int j = 0; j < 4; ++j) {
    float den = __shfl(acc2[4][j], (lane & 48));
    dinv[j] = 1.f / den;
  }
#pragma unroll
  for (int n = 0; n < 4; ++n)
#pragma unroll
    for (int j = 0; j < 4; ++j) {
      int l = orow + fq * 4 + j;
      int col = h * 64 + n * 16 + fr;
      attn[(tokb + l) * DIM_ + col] = f2bf(acc2[n][j] * dinv[j]);
    }
}

// ---------------- output projection: BN=64, dbuf single-barrier (r12 best); fp32 out ----------------
__global__ __launch_bounds__(256) void gemmo_k(const ushort_t* __restrict__ A, const ushort_t* __restrict__ Bw,
                                               const float* __restrict__ bias, float* __restrict__ Y) {
  __shared__ char SB[49152];
  const int tid = threadIdx.x, lane = tid & 63, w = tid >> 6;
  const int bm = blockIdx.x * 128, bn = blockIdx.y * 64;
  const int srow = w * 8 + (lane >> 3);
  const int scol = (((lane & 7) * 16) ^ ((lane >> 3) << 4)) >> 1;
  const int wr = (w >> 1) * 64, wc = (w & 1) * 32;
  const int fr = lane & 15, ks = lane >> 4, fq = lane >> 4;
  f4v acc[4][2] = {};
#pragma unroll
  for (int i = 0; i < 4; ++i)
    gll16(A + (size_t)(bm + i * 32 + srow) * DIM_ + scol, SB + i * 4096 + w * 1024);
#pragma unroll
  for (int i = 0; i < 2; ++i)
    gll16(Bw + (size_t)(bn + i * 32 + srow) * DIM_ + scol, SB + 32768 + i * 4096 + w * 1024);
  __syncthreads();
  for (int t = 0; t < 8; ++t) {
    const ushort_t* curA = (const ushort_t*)(SB + (t & 1) * 16384);
    const ushort_t* curB = (const ushort_t*)(SB + 32768 + (t & 1) * 8192);
    char* nxtA = SB + ((t + 1) & 1) * 16384;
    char* nxtB = SB + 32768 + ((t + 1) & 1) * 8192;
    const int nk = (t + 1) * 64;
    if (t < 7) {
#pragma unroll
      for (int i = 0; i < 4; ++i)
        gll16(A + (size_t)(bm + i * 32 + srow) * DIM_ + nk + scol, nxtA + i * 4096 + w * 1024);
#pragma unroll
      for (int i = 0; i < 2; ++i)
        gll16(Bw + (size_t)(bn + i * 32 + srow) * DIM_ + nk + scol, nxtB + i * 4096 + w * 1024);
    }
#pragma unroll
    for (int kk = 0; kk < 2; ++kk) {
      const int cb = kk * 64 + ks * 16;
      bf8v av[4], bv[2];
#pragma unroll
      for (int m = 0; m < 4; ++m) av[m] = ldfrag(curA, wr + m * 16 + fr, cb);
#pragma unroll
      for (int n = 0; n < 2; ++n) bv[n] = ldfrag(curB, wc + n * 16 + fr, cb);
#pragma unroll
      for (int m = 0; m < 4; ++m)
#pragma unroll
        for (int n = 0; n < 2; ++n) acc[m][n] = MFMA16(av[m], bv[n], acc[m][n]);
    }
    __syncthreads();
  }
#pragma unroll
  for (int m = 0; m < 4; ++m)
#pragma unroll
    for (int n = 0; n < 2; ++n) {
      int col = bn + wc + n * 16 + fr;
      float bsv = bias[col];
#pragma unroll
      for (int j = 0; j < 4; ++j) {
        int row = bm + wr + m * 16 + fq * 4 + j;
        Y[(size_t)row * DIM_ + col] = acc[m][n][j] + bsv;
      }
    }
}

extern "C" void kernel_launch(void* const* d_in, const int* in_sizes, int n_in,
                              void* d_out, int out_size, void* d_ws, size_t ws_size,
                              hipStream_t stream) {
  const float* query = (const float*)d_in[0];
  const float* key   = (const float*)d_in[1];
  const float* value = (const float*)d_in[2];
  const float* proj  = (const float*)d_in[3];
  const float* wq = (const float*)d_in[4];
  const float* bq = (const float*)d_in[5];
  const float* wk = (const float*)d_in[6];
  const float* bk = (const float*)d_in[7];
  const float* wv = (const float*)d_in[8];
  const float* bv = (const float*)d_in[9];
  const float* wo = (const float*)d_in[10];
  const float* bo = (const float*)d_in[11];

  char* ws = (char*)d_ws;
  ushort_t* Wc   = (ushort_t*)(ws);                 // weights+proj bf16: 2,129,920 B
  ushort_t* Xq   = (ushort_t*)(ws + 2129920);       // 8 MB
  ushort_t* Xk   = (ushort_t*)(ws + 10518528);      // 8 MB
  ushort_t* Xv   = (ushort_t*)(ws + 18907136);      // 8 MB
  ushort_t* XHq  = (ushort_t*)(ws + 27295744);      // 8 MB
  ushort_t* XHk  = (ushort_t*)(ws + 35684352);      // 8 MB
  ushort_t* VT   = (ushort_t*)(ws + 44072960);      // 8 MB [bh][64][2048]
  ushort_t* Skv  = (ushort_t*)(ws + 52461568);      // 17.04 MB [bh][16][65][256]
  ushort_t* attb = (ushort_t*)(ws + 69500928);      // 8 MB
  const ushort_t* Wo = Wc + 786432;
  const ushort_t* Pc = Wc + 1048576;

  dim3 blk(256);
  cvt_all<<<6664, blk, 0, stream>>>(query, key, value, wq, wk, wv, wo, proj, Xq, Xk, Xv, Wc);
  qkvgemm_k<<<dim3(64, 2, 3), dim3(512), 0, stream>>>(Xq, Xk, Xv, Wc, bq, bk, bv, XHq, XHk, VT);
  cp2_k<<<dim3(NC, BH), blk, 0, stream>>>(XHk, Pc, VT, Skv);
  prefix2_k<<<260, blk, 0, stream>>>(Skv);
  qkout4_k<<<dim3(NC, BH), dim3(512), 0, stream>>>(XHq, XHk, Pc, VT, Skv, attb);
  gemmo_k<<<dim3(64, 8), blk, 0, stream>>>(attb, Wo, bo, (float*)d_out);
}

// Round 17
// 91.918 us; speedup vs baseline: 1.0795x; 1.0795x over previous
//
#include <hip/hip_runtime.h>
#include <stdint.h>

#define B_ 4
#define L_ 2048
#define H_ 8
#define DK 64
#define M_ 256
#define DIM_ 512
#define NTOK (B_ * L_)
#define CHK 128
#define NC (L_ / CHK)
#define BH (B_ * H_)
#define RATIO 0.0625f
#define STABC 1e-5f

typedef unsigned short ushort_t;
typedef __attribute__((ext_vector_type(8))) short bf8v;   // 8 bf16 = 4 VGPR
typedef __attribute__((ext_vector_type(4))) float f4v;    // MFMA accumulator

#define MFMA16(a, b, c) __builtin_amdgcn_mfma_f32_16x16x32_bf16(a, b, c, 0, 0, 0)

__device__ __forceinline__ ushort_t f2bf(float f) {
  uint32_t u = __float_as_uint(f);
  return (ushort_t)((u + 0x7fffu + ((u >> 16) & 1u)) >> 16);
}
__device__ __forceinline__ float bf2f(ushort_t u) { return __uint_as_float(((uint32_t)u) << 16); }

__device__ __forceinline__ void gll16(const void* g, void* l) {
  __builtin_amdgcn_global_load_lds((const __attribute__((address_space(1))) void*)g,
                                   (__attribute__((address_space(3))) void*)l, 16, 0, 0);
}

// XOR-swizzled LDS tiles; row strides 128/256/512 B
__device__ __forceinline__ bf8v ldfrag(const ushort_t* base, int row, int cb) {
  return *(const bf8v*)((const char*)base + row * 128 + (cb ^ ((row & 7) << 4)));
}
__device__ __forceinline__ bf8v ldfrag256(const ushort_t* base, int row, int cb) {
  return *(const bf8v*)((const char*)base + row * 256 + (cb ^ ((row & 7) << 4)));
}
__device__ __forceinline__ bf8v ldfrag512(const ushort_t* base, int row, int cb) {
  return *(const bf8v*)((const char*)base + row * 512 + (cb ^ ((row & 7) << 4)));
}

// ---------------- bf16 convert of weights + proj only ----------------
__global__ __launch_bounds__(256) void cvt_w(const float* __restrict__ wq, const float* __restrict__ wk,
                                             const float* __restrict__ wv, const float* __restrict__ wo,
                                             const float* __restrict__ pj, ushort_t* __restrict__ d) {
  int i = (blockIdx.x * 256 + threadIdx.x) * 8;   // 520 blocks covers 1,064,960 elems exactly
  const float* s;
  int off;
  if (i < 262144)       { s = wq; off = i; }
  else if (i < 524288)  { s = wk; off = i - 262144; }
  else if (i < 786432)  { s = wv; off = i - 524288; }
  else if (i < 1048576) { s = wo; off = i - 786432; }
  else                  { s = pj; off = i - 1048576; }
  float4 a = *(const float4*)(s + off);
  float4 b = *(const float4*)(s + off + 4);
  union { ushort_t u[8]; uint4 vv; } o;
  o.u[0] = f2bf(a.x); o.u[1] = f2bf(a.y); o.u[2] = f2bf(a.z); o.u[3] = f2bf(a.w);
  o.u[4] = f2bf(b.x); o.u[5] = f2bf(b.y); o.u[6] = f2bf(b.z); o.u[7] = f2bf(b.w);
  *(uint4*)(d + i) = o.vv;
}

// ---------------- Q/K/V projection GEMM: 128x256 tile, BK=64, 512 threads (r13/r15 best) ----------------
// grid (64, 2, 3): z=0 query->XHq, z=1 key->XHk, z=2 value->VT (transposed head-slices)
__global__ __launch_bounds__(512) void qkvgemm_k(const float* __restrict__ q, const float* __restrict__ k,
                                                 const float* __restrict__ v, const ushort_t* __restrict__ Wc,
                                                 const float* __restrict__ bq, const float* __restrict__ bk,
                                                 const float* __restrict__ bv, ushort_t* __restrict__ XHq,
                                                 ushort_t* __restrict__ XHk, ushort_t* __restrict__ VT) {
  __shared__ char SB[49152];           // A bf16 [128][64] swz @0 (16K); B bf16 [256][64] swz @16384 (32K)
  ushort_t* Tt = (ushort_t*)SB;        // epilogue alias [128][136] = 34816 B (z==2)
  const int z = blockIdx.z;
  const float* X = (z == 0) ? q : (z == 1) ? k : v;
  const ushort_t* Bw = Wc + (size_t)z * 262144;
  const float* bias = (z == 0) ? bq : (z == 1) ? bk : bv;
  const int tid = threadIdx.x, lane = tid & 63, w = tid >> 6;   // w 0..7
  const int bm = blockIdx.x * 128, bn = blockIdx.y * 256;
  const int scol = (((lane & 7) * 16) ^ ((lane >> 3) << 4)) >> 1;   // pre-swizzled source elem
  const int fr = lane & 15, ks = lane >> 4, fq = lane >> 4;
  const int wr = (w >> 2) * 64, wc = (w & 3) * 64;
  f4v acc[4][4] = {};
  for (int t = 0; t < 8; ++t) {
    const int k0 = t * 64;
    // B (weights, bf16): 256 rows x 128B; wave w covers rows w*32 + i*8 + (lane>>3)
#pragma unroll
    for (int i = 0; i < 4; ++i)
      gll16(Bw + (size_t)(bn + w * 32 + i * 8 + (lane >> 3)) * DIM_ + k0 + scol,
            SB + 16384 + w * 4096 + i * 1024);
    // A (fp32 -> bf16, swizzled ds_write): 128 rows x 64 k
#pragma unroll
    for (int i = 0; i < 2; ++i) {
      int e = tid + i * 512;
      int r = e >> 3, g = e & 7;
      const float* src = X + (size_t)(bm + r) * DIM_ + k0 + g * 8;
      float4 f0 = *(const float4*)src;
      float4 f1 = *(const float4*)(src + 4);
      union { ushort_t u[8]; bf8v v8; } pk;
      pk.u[0] = f2bf(f0.x); pk.u[1] = f2bf(f0.y); pk.u[2] = f2bf(f0.z); pk.u[3] = f2bf(f0.w);
      pk.u[4] = f2bf(f1.x); pk.u[5] = f2bf(f1.y); pk.u[6] = f2bf(f1.z); pk.u[7] = f2bf(f1.w);
      *(bf8v*)(SB + r * 128 + ((g * 16) ^ ((r & 7) << 4))) = pk.v8;
    }
    __syncthreads();
#pragma unroll
    for (int kk = 0; kk < 2; ++kk) {
      const int cb = kk * 64 + ks * 16;
      bf8v av[4], bv2[4];
#pragma unroll
      for (int m = 0; m < 4; ++m) av[m] = ldfrag((const ushort_t*)SB, wr + m * 16 + fr, cb);
#pragma unroll
      for (int n = 0; n < 4; ++n) bv2[n] = ldfrag((const ushort_t*)(SB + 16384), wc + n * 16 + fr, cb);
#pragma unroll
      for (int m = 0; m < 4; ++m)
#pragma unroll
        for (int n = 0; n < 4; ++n) acc[m][n] = MFMA16(av[m], bv2[n], acc[m][n]);
    }
    __syncthreads();
  }
  if (z == 2) {   // V path: transpose 256-col head slice -> VT[bh][64][2048], two 128-col halves
    for (int hh = 0; hh < 2; ++hh) {
      if (((w & 3) >> 1) == hh) {
        const int wcl = wc - hh * 128;   // 0 or 64
#pragma unroll
        for (int m = 0; m < 4; ++m)
#pragma unroll
          for (int n = 0; n < 4; ++n) {
            int cl = wcl + n * 16 + fr;
            float bsv = bias[bn + wc + n * 16 + fr];
#pragma unroll
            for (int j = 0; j < 4; ++j) {
              int rl = wr + m * 16 + fq * 4 + j;
              Tt[cl * 136 + rl] = f2bf(acc[m][n][j] + bsv);
            }
          }
      }
      __syncthreads();
      const int dl = tid >> 2, seg = tid & 3;
      const int c = bn + hh * 128 + dl;            // global dim col 0..511
      const int bh2 = (bm >> 11) * 8 + (c >> 6);
      const int drow = c & 63;
      size_t vbase = ((size_t)(bh2 * 64 + drow)) * L_ + (bm & 2047) + seg * 32;
#pragma unroll
      for (int qq = 0; qq < 4; ++qq)
        *(uint4*)&VT[vbase + qq * 8] = *(const uint4*)&Tt[dl * 136 + seg * 32 + qq * 8];
      __syncthreads();
    }
  } else {
    ushort_t* Y = (z == 0) ? XHq : XHk;
#pragma unroll
    for (int m = 0; m < 4; ++m)
#pragma unroll
      for (int n = 0; n < 4; ++n) {
        int col = bn + wc + n * 16 + fr;
        float bsv = bias[col];
#pragma unroll
        for (int j = 0; j < 4; ++j) {
          int row = bm + wr + m * 16 + fq * 4 + j;
          Y[(size_t)row * DIM_ + col] = f2bf(acc[m][n][j] + bsv);
        }
      }
  }
}

// ---------------- cp2: fused kp-feature + per-chunk partials (no kp store) ----------------
__global__ __launch_bounds__(256) void cp2_k(const ushort_t* __restrict__ XHk, const ushort_t* __restrict__ P,
                                             const ushort_t* __restrict__ VT, ushort_t* __restrict__ S) {
  __shared__ ushort_t Ps[256 * 64];    // proj (32 KB)
  __shared__ ushort_t Xs[128 * 64];    // XHk chunk, then [VT;ones] (16 KB)
  __shared__ ushort_t Kt[256 * 128];   // kpT [m][l], 256B rows swizzled (64 KB)
  const int ci = blockIdx.x, bh = blockIdx.y;
  const int b = bh >> 3, h = bh & 7;
  const int tid = threadIdx.x, lane = tid & 63, w = tid >> 6;
  const int srow = w * 8 + (lane >> 3);
  const int scol = (((lane & 7) * 16) ^ ((lane >> 3) << 4)) >> 1;
  const int fr = lane & 15, ks = lane >> 4, fq = lane >> 4;
  const int l0 = ci * CHK;
#pragma unroll
  for (int i = 0; i < 8; ++i)
    gll16(P + (size_t)(i * 32 + srow) * 64 + scol, (char*)Ps + i * 4096 + w * 1024);
#pragma unroll
  for (int i = 0; i < 4; ++i)
    gll16(XHk + (size_t)(b * L_ + l0 + i * 32 + srow) * DIM_ + h * 64 + scol, (char*)Xs + i * 4096 + w * 1024);
  __syncthreads();
  {
    f4v acc[4][8] = {};
#pragma unroll
    for (int kk = 0; kk < 2; ++kk) {
      const int cb = kk * 64 + ks * 16;
      bf8v av[4], bv[8];
#pragma unroll
      for (int m = 0; m < 4; ++m) av[m] = ldfrag(Ps, w * 64 + m * 16 + fr, cb);
#pragma unroll
      for (int n = 0; n < 8; ++n) bv[n] = ldfrag(Xs, n * 16 + fr, cb);
#pragma unroll
      for (int m = 0; m < 4; ++m)
#pragma unroll
        for (int n = 0; n < 8; ++n) acc[m][n] = MFMA16(av[m], bv[n], acc[m][n]);
    }
#pragma unroll
    for (int m = 0; m < 4; ++m)
#pragma unroll
      for (int n = 0; n < 8; ++n) {
        const int mb = w * 64 + m * 16 + fq * 4;
        const int ll = n * 16 + fr;
#pragma unroll
        for (int j = 0; j < 4; ++j) {
          float v = fmaxf(RATIO * acc[m][n][j], 0.f) + STABC;
          *(ushort_t*)((char*)Kt + (mb + j) * 256 + ((ll * 2) ^ (((mb + j) & 7) << 4))) = f2bf(v);
        }
      }
  }
  __syncthreads();
  f4v accS[5][4] = {};
  for (int kt = 0; kt < 2; ++kt) {
#pragma unroll
    for (int i = 0; i < 2; ++i)
      gll16(VT + ((size_t)bh * 64 + i * 32 + srow) * L_ + l0 + kt * 64 + scol, (char*)Xs + i * 4096 + w * 1024);
    if (tid < 32) ((uint32_t*)Xs)[2048 + tid] = 0x3f803f80u;
    __syncthreads();
#pragma unroll
    for (int kk = 0; kk < 2; ++kk) {
      const int cbA = kk * 64 + ks * 16;
      const int cbK = kt * 128 + kk * 64 + ks * 16;
      bf8v av[5], bv[4];
#pragma unroll
      for (int a = 0; a < 5; ++a) av[a] = ldfrag(Xs, a * 16 + fr, cbA);
#pragma unroll
      for (int n = 0; n < 4; ++n) bv[n] = ldfrag256(Kt, w * 64 + n * 16 + fr, cbK);
#pragma unroll
      for (int a = 0; a < 5; ++a)
#pragma unroll
        for (int n = 0; n < 4; ++n) accS[a][n] = MFMA16(av[a], bv[n], accS[a][n]);
    }
    __syncthreads();
  }
  const size_t base = ((size_t)bh * NC + ci) * 65;
#pragma unroll
  for (int a = 0; a < 5; ++a)
#pragma unroll
    for (int n = 0; n < 4; ++n)
#pragma unroll
      for (int j = 0; j < 4; ++j) {
        int row = a * 16 + fq * 4 + j;
        if (row < 65) S[(base + row) * M_ + w * 64 + n * 16 + fr] = f2bf(accS[a][n][j]);
      }
}

// ---------------- exclusive prefix over chunks ----------------
__global__ __launch_bounds__(256) void prefix2_k(ushort_t* __restrict__ S) {
  const int g = blockIdx.x * 256 + threadIdx.x;
  const int bh = g / 2080, r = g - bh * 2080;
  ushort_t* base = S + (size_t)bh * (NC * 65 * M_) + (size_t)r * 8;
  uint4 v[16];
#pragma unroll
  for (int ci = 0; ci < NC; ++ci) v[ci] = *(const uint4*)(base + (size_t)ci * (65 * M_));
  float c[8] = {};
#pragma unroll
  for (int ci = 0; ci < NC; ++ci) {
    union { uint4 u; ushort_t s[8]; } in, out;
    in.u = v[ci];
#pragma unroll
    for (int e = 0; e < 8; ++e) {
      float t = bf2f(in.s[e]);
      out.s[e] = f2bf(c[e]);
      c[e] += t;
    }
    *(uint4*)(base + (size_t)ci * (65 * M_)) = out.u;
  }
}

// ---------------- qkout4: in-LDS qp AND kp features + QK^T + qp@S + A@[VT;1] ----------------
__global__ __launch_bounds__(512) void qkout4_k(const ushort_t* __restrict__ XHq, const ushort_t* __restrict__ XHk,
                                                const ushort_t* __restrict__ P, const ushort_t* __restrict__ VT,
                                                const ushort_t* __restrict__ S, ushort_t* __restrict__ attn) {
  __shared__ char LB[147456];
  ushort_t* Qp  = (ushort_t*)LB;
  ushort_t* Pj  = (ushort_t*)(LB + 65536);   // At aliases this in phases 2/3
  ushort_t* Kps = (ushort_t*)(LB + 98304);
  ushort_t* R2  = (ushort_t*)(LB + 114688);
  ushort_t* Xk  = (ushort_t*)(LB + 131072);
  const int ci = blockIdx.x, bh = blockIdx.y;
  const int b = bh >> 3, h = bh & 7;
  const int tid = threadIdx.x, lane = tid & 63, w = tid >> 6;   // w 0..7
  const int srow = w * 8 + (lane >> 3);
  const int scol = (((lane & 7) * 16) ^ ((lane >> 3) << 4)) >> 1;
  const int fr = lane & 15, ks = lane >> 4, fq = lane >> 4;
  const int l0 = ci * CHK;
  const size_t tokb = (size_t)b * L_ + l0;
  const size_t sbase = ((size_t)bh * NC + ci) * 65;
  // ---- phase 0: stage proj + XHq + XHk; compute Qp ----
#pragma unroll
  for (int i = 0; i < 4; ++i)
    gll16(P + (size_t)(i * 64 + srow) * 64 + scol, (char*)Pj + i * 8192 + w * 1024);
#pragma unroll
  for (int i = 0; i < 2; ++i) {
    gll16(XHq + (tokb + i * 64 + srow) * DIM_ + h * 64 + scol, (char*)R2 + i * 8192 + w * 1024);
    gll16(XHk + (tokb + i * 64 + srow) * DIM_ + h * 64 + scol, (char*)Xk + i * 8192 + w * 1024);
  }
  __syncthreads();
  {
    f4v accF[2][8] = {};
#pragma unroll
    for (int kk = 0; kk < 2; ++kk) {
      const int cb = kk * 64 + ks * 16;
      bf8v av[2], bv[8];
#pragma unroll
      for (int m = 0; m < 2; ++m) av[m] = ldfrag(Pj, w * 32 + m * 16 + fr, cb);
#pragma unroll
      for (int n = 0; n < 8; ++n) bv[n] = ldfrag(R2, n * 16 + fr, cb);
#pragma unroll
      for (int m = 0; m < 2; ++m)
#pragma unroll
        for (int n = 0; n < 8; ++n) accF[m][n] = MFMA16(av[m], bv[n], accF[m][n]);
    }
#pragma unroll
    for (int m = 0; m < 2; ++m)
#pragma unroll
      for (int n = 0; n < 8; ++n) {
        const int mb = w * 32 + m * 16 + fq * 4;
        const int ll = n * 16 + fr;
        ushort_t bvv[4];
#pragma unroll
        for (int j = 0; j < 4; ++j)
          bvv[j] = f2bf(fmaxf(RATIO * accF[m][n][j], 0.f) + STABC);
        uint2 pk;
        pk.x = (uint32_t)bvv[0] | ((uint32_t)bvv[1] << 16);
        pk.y = (uint32_t)bvv[2] | ((uint32_t)bvv[3] << 16);
        *(uint2*)((char*)Qp + ll * 512 + ((mb * 2) ^ ((ll & 7) << 4))) = pk;
      }
  }
  __syncthreads();
  // ---- phase 1: per kt: Kp slice (in-LDS feat) + QK^T + qp@[S;sk] ----
  const int qr = (w & 3) * 32, qc = (w >> 2) * 64;
  const int orow = w * 16;
  f4v accA[2][4] = {};
  f4v acc2[5] = {};
  for (int kt = 0; kt < 4; ++kt) {
    gll16(S + (sbase + srow) * M_ + kt * 64 + scol, (char*)R2 + w * 1024);
    if (tid < 32)
      ((uint32_t*)R2)[2048 + tid] = ((const uint32_t*)(S + (sbase + 64) * M_ + kt * 64))[tid];
    {
      const int fi = w >> 1, tf0 = (w & 1) * 4;
      f4v accK[4] = {};
#pragma unroll
      for (int kk = 0; kk < 2; ++kk) {
        const int cb = kk * 64 + ks * 16;
        bf8v ap = ldfrag(Pj, kt * 64 + fi * 16 + fr, cb);
        bf8v bx[4];
#pragma unroll
        for (int t2 = 0; t2 < 4; ++t2) bx[t2] = ldfrag(Xk, (tf0 + t2) * 16 + fr, cb);
#pragma unroll
        for (int t2 = 0; t2 < 4; ++t2) accK[t2] = MFMA16(ap, bx[t2], accK[t2]);
      }
#pragma unroll
      for (int t2 = 0; t2 < 4; ++t2) {
        const int tt = (tf0 + t2) * 16 + fr;
        const int fl = fi * 16 + fq * 4;
#pragma unroll
        for (int j = 0; j < 4; ++j) {
          float v = fmaxf(RATIO * accK[t2][j], 0.f) + STABC;
          *(ushort_t*)((char*)Kps + tt * 128 + (((fl + j) * 2) ^ ((tt & 7) << 4))) = f2bf(v);
        }
      }
    }
    __syncthreads();
#pragma unroll
    for (int kk = 0; kk < 2; ++kk) {
      const int cb = kk * 64 + ks * 16;
      const int cbQ = kt * 128 + cb;
      bf8v aq[2], bk_[4], a2, sv[5];
#pragma unroll
      for (int m = 0; m < 2; ++m) aq[m] = ldfrag512(Qp, qr + m * 16 + fr, cbQ);
#pragma unroll
      for (int n = 0; n < 4; ++n) bk_[n] = ldfrag(Kps, qc + n * 16 + fr, cb);
#pragma unroll
      for (int m = 0; m < 2; ++m)
#pragma unroll
        for (int n = 0; n < 4; ++n) accA[m][n] = MFMA16(aq[m], bk_[n], accA[m][n]);
      a2 = ldfrag512(Qp, orow + fr, cbQ);
#pragma unroll
      for (int n = 0; n < 5; ++n) sv[n] = ldfrag(R2, n * 16 + fr, cb);
#pragma unroll
      for (int n = 0; n < 5; ++n) acc2[n] = MFMA16(a2, sv[n], acc2[n]);
    }
    __syncthreads();
  }
  // ---- phase 2: masked A -> At (aliases Pj) ----
#pragma unroll
  for (int m = 0; m < 2; ++m)
#pragma unroll
    for (int n = 0; n < 4; ++n)
#pragma unroll
      for (int j = 0; j < 4; ++j) {
        int row = qr + m * 16 + fq * 4 + j;
        int col = qc + n * 16 + fr;
        float v = (col <= row) ? accA[m][n][j] : 0.f;
        *(ushort_t*)((char*)Pj + row * 256 + ((col * 2) ^ ((row & 7) << 4))) = f2bf(v);
      }
  __syncthreads();
  // ---- phase 3: A @ [VT; ones] ----
  for (int kt2 = 0; kt2 < 2; ++kt2) {
    gll16(VT + ((size_t)bh * 64 + srow) * L_ + l0 + kt2 * 64 + scol, (char*)R2 + w * 1024);
    if (tid < 32) ((uint32_t*)R2)[2048 + tid] = 0x3f803f80u;
    __syncthreads();
#pragma unroll
    for (int kk = 0; kk < 2; ++kk) {
      const int cb = kk * 64 + ks * 16;
      bf8v a3, sv[5];
      a3 = ldfrag256(Pj, orow + fr, kt2 * 128 + cb);
#pragma unroll
      for (int n = 0; n < 5; ++n) sv[n] = ldfrag(R2, n * 16 + fr, cb);
#pragma unroll
      for (int n = 0; n < 5; ++n) acc2[n] = MFMA16(a3, sv[n], acc2[n]);
    }
    __syncthreads();
  }
  // ---- epilogue ----
  float dinv[4];
#pragma unroll
  for (int j = 0; j < 4; ++j) {
    float den = __shfl(acc2[4][j], (lane & 48));
    dinv[j] = 1.f / den;
  }
#pragma unroll
  for (int n = 0; n < 4; ++n)
#pragma unroll
    for (int j = 0; j < 4; ++j) {
      int l = orow + fq * 4 + j;
      int col = h * 64 + n * 16 + fr;
      attn[(tokb + l) * DIM_ + col] = f2bf(acc2[n][j] * dinv[j]);
    }
}

// ---------------- output projection: BN=64, dbuf single-barrier (r12 best); fp32 out ----------------
__global__ __launch_bounds__(256) void gemmo_k(const ushort_t* __restrict__ A, const ushort_t* __restrict__ Bw,
                                               const float* __restrict__ bias, float* __restrict__ Y) {
  __shared__ char SB[49152];
  const int tid = threadIdx.x, lane = tid & 63, w = tid >> 6;
  const int bm = blockIdx.x * 128, bn = blockIdx.y * 64;
  const int srow = w * 8 + (lane >> 3);
  const int scol = (((lane & 7) * 16) ^ ((lane >> 3) << 4)) >> 1;
  const int wr = (w >> 1) * 64, wc = (w & 1) * 32;
  const int fr = lane & 15, ks = lane >> 4, fq = lane >> 4;
  f4v acc[4][2] = {};
#pragma unroll
  for (int i = 0; i < 4; ++i)
    gll16(A + (size_t)(bm + i * 32 + srow) * DIM_ + scol, SB + i * 4096 + w * 1024);
#pragma unroll
  for (int i = 0; i < 2; ++i)
    gll16(Bw + (size_t)(bn + i * 32 + srow) * DIM_ + scol, SB + 32768 + i * 4096 + w * 1024);
  __syncthreads();
  for (int t = 0; t < 8; ++t) {
    const ushort_t* curA = (const ushort_t*)(SB + (t & 1) * 16384);
    const ushort_t* curB = (const ushort_t*)(SB + 32768 + (t & 1) * 8192);
    char* nxtA = SB + ((t + 1) & 1) * 16384;
    char* nxtB = SB + 32768 + ((t + 1) & 1) * 8192;
    const int nk = (t + 1) * 64;
    if (t < 7) {
#pragma unroll
      for (int i = 0; i < 4; ++i)
        gll16(A + (size_t)(bm + i * 32 + srow) * DIM_ + nk + scol, nxtA + i * 4096 + w * 1024);
#pragma unroll
      for (int i = 0; i < 2; ++i)
        gll16(Bw + (size_t)(bn + i * 32 + srow) * DIM_ + nk + scol, nxtB + i * 4096 + w * 1024);
    }
#pragma unroll
    for (int kk = 0; kk < 2; ++kk) {
      const int cb = kk * 64 + ks * 16;
      bf8v av[4], bv[2];
#pragma unroll
      for (int m = 0; m < 4; ++m) av[m] = ldfrag(curA, wr + m * 16 + fr, cb);
#pragma unroll
      for (int n = 0; n < 2; ++n) bv[n] = ldfrag(curB, wc + n * 16 + fr, cb);
#pragma unroll
      for (int m = 0; m < 4; ++m)
#pragma unroll
        for (int n = 0; n < 2; ++n) acc[m][n] = MFMA16(av[m], bv[n], acc[m][n]);
    }
    __syncthreads();
  }
#pragma unroll
  for (int m = 0; m < 4; ++m)
#pragma unroll
    for (int n = 0; n < 2; ++n) {
      int col = bn + wc + n * 16 + fr;
      float bsv = bias[col];
#pragma unroll
      for (int j = 0; j < 4; ++j) {
        int row = bm + wr + m * 16 + fq * 4 + j;
        Y[(size_t)row * DIM_ + col] = acc[m][n][j] + bsv;
      }
    }
}

extern "C" void kernel_launch(void* const* d_in, const int* in_sizes, int n_in,
                              void* d_out, int out_size, void* d_ws, size_t ws_size,
                              hipStream_t stream) {
  const float* query = (const float*)d_in[0];
  const float* key   = (const float*)d_in[1];
  const float* value = (const float*)d_in[2];
  const float* proj  = (const float*)d_in[3];
  const float* wq = (const float*)d_in[4];
  const float* bq = (const float*)d_in[5];
  const float* wk = (const float*)d_in[6];
  const float* bk = (const float*)d_in[7];
  const float* wv = (const float*)d_in[8];
  const float* bv = (const float*)d_in[9];
  const float* wo = (const float*)d_in[10];
  const float* bo = (const float*)d_in[11];

  char* ws = (char*)d_ws;
  ushort_t* Wc   = (ushort_t*)(ws);                 // weights+proj bf16: 2,129,920 B
  ushort_t* XHq  = (ushort_t*)(ws + 2129920);       // 8 MB
  ushort_t* XHk  = (ushort_t*)(ws + 10518528);      // 8 MB
  ushort_t* VT   = (ushort_t*)(ws + 18907136);      // 8 MB [bh][64][2048]
  ushort_t* Skv  = (ushort_t*)(ws + 27295744);      // 17.04 MB [bh][16][65][256]
  ushort_t* attb = (ushort_t*)(ws + 44335104);      // 8 MB
  const ushort_t* Wo = Wc + 786432;
  const ushort_t* Pc = Wc + 1048576;

  dim3 blk(256);
  cvt_w<<<520, blk, 0, stream>>>(wq, wk, wv, wo, proj, Wc);
  qkvgemm_k<<<dim3(64, 2, 3), dim3(512), 0, stream>>>(query, key, value, Wc, bq, bk, bv, XHq, XHk, VT);
  cp2_k<<<dim3(NC, BH), blk, 0, stream>>>(XHk, Pc, VT, Skv);
  prefix2_k<<<260, blk, 0, stream>>>(Skv);
  qkout4_k<<<dim3(NC, BH), dim3(512), 0, stream>>>(XHq, XHk, Pc, VT, Skv, attb);
  gemmo_k<<<dim3(64, 8), blk, 0, stream>>>(attb, Wo, bo, (float*)d_out);
}